// Round 1
// baseline (980.110 us; speedup 1.0000x reference)
//
#include <hip/hip_runtime.h>
#include <stdint.h>

#define HW 16384
#define CDIM 768
#define EPSF 1e-8f

typedef __bf16 bf16;
typedef __bf16 bf16x8 __attribute__((ext_vector_type(8)));
typedef float f32x4 __attribute__((ext_vector_type(4)));

__device__ inline void async16(const bf16* g, bf16* l) {
    __builtin_amdgcn_global_load_lds(
        (const __attribute__((address_space(1))) uint32_t*)g,
        (__attribute__((address_space(3))) uint32_t*)l, 16, 0, 0);
}

// ---- Kernel 1: column norms of b (two-eps scheme) ----
// grid 256 blocks x 256 threads; 64 j per block, 4 c-threads each
__global__ void colnorm_b(const float* __restrict__ b,
                          float* __restrict__ denom_b,
                          float* __restrict__ nb_raw) {
    __shared__ float red[4][64];
    int tx = threadIdx.x & 63, ty = threadIdx.x >> 6;
    int j = blockIdx.x * 64 + tx;
    float s = 0.f;
    for (int c = ty; c < CDIM; c += 4) {
        float v = b[(size_t)c * HW + j];
        s = fmaf(v, v, s);
    }
    red[ty][tx] = s;
    __syncthreads();
    if (ty == 0) {
        s = red[0][tx] + red[1][tx] + red[2][tx] + red[3][tx];
        denom_b[j] = sqrtf(s + EPSF) + EPSF;   // matches reference b_n denominator
        nb_raw[j]  = sqrtf(s);                  // cos_loss's norm (eps outside)
    }
}

// ---- Kernel 2: transpose [C][HW] fp32 -> [HW][C] bf16, optional per-column scale ----
// tile 64x64, LDS-staged; grid (256 s-tiles, 12 c-tiles), 256 threads
__global__ void transpose_scale(const float* __restrict__ src,
                                bf16* __restrict__ dst,
                                const float* __restrict__ denom) {
    __shared__ float tile[64][65];   // +1 pad: conflict-free
    int s0 = blockIdx.x * 64, c0 = blockIdx.y * 64;
    int tx = threadIdx.x & 63, ty = threadIdx.x >> 6;
#pragma unroll
    for (int p = 0; p < 16; ++p) {
        int cl = p * 4 + ty;
        tile[cl][tx] = src[(size_t)(c0 + cl) * HW + s0 + tx];
    }
    __syncthreads();
#pragma unroll
    for (int p = 0; p < 16; ++p) {
        int sl = p * 4 + ty;
        float sc = denom ? (1.0f / denom[s0 + sl]) : 1.0f;
        float v = tile[tx][sl] * sc;
        dst[(size_t)(s0 + sl) * CDIM + c0 + tx] = (bf16)v;
    }
}

// ---- Kernel 3: GEMM (a_t[i][c] . bn_t[j][c]) with argmax-over-j epilogue ----
// 128x128 tile, BK=32, 4 waves (2x2), 4x4 frags of mfma_f32_16x16x32_bf16
__global__ void __launch_bounds__(256)
gemm_argmax(const bf16* __restrict__ at, const bf16* __restrict__ bnt,
            unsigned long long* __restrict__ best) {
    __shared__ bf16 Al[128 * 32];
    __shared__ bf16 Bl[128 * 32];
    const int it = blockIdx.x >> 7, jt = blockIdx.x & 127;
    const int i0 = it * 128, j0 = jt * 128;
    const int tid = threadIdx.x;
    const int lane = tid & 63, w = tid >> 6;
    const int wi = w & 1, wj = w >> 1;
    const int quad = lane >> 4, l15 = lane & 15;

    f32x4 acc[4][4] = {};

    // staging: wave w covers rows [w*32, w*32+32) of each 128-row tile,
    // in two 16-row issues; lane l -> row (l>>2), 16B chunk (l&3)
    const int srow = (lane >> 2);
    const int scol = (lane & 3) * 8;
    const bf16* gA = at + (size_t)(i0 + w * 32 + srow) * CDIM + scol;
    const bf16* gB = bnt + (size_t)(j0 + w * 32 + srow) * CDIM + scol;
    bf16* lA = &Al[(w * 32) * 32];
    bf16* lB = &Bl[(w * 32) * 32];

    for (int kk = 0; kk < CDIM; kk += 32) {
        async16(gA + kk,            lA);
        async16(gA + 16 * CDIM + kk, lA + 16 * 32);
        async16(gB + kk,            lB);
        async16(gB + 16 * CDIM + kk, lB + 16 * 32);
        __syncthreads();   // drains vmcnt (global_load_lds) + barrier

        bf16x8 af[4], bg[4];
#pragma unroll
        for (int m = 0; m < 4; ++m)
            af[m] = *(const bf16x8*)&Al[(wi * 64 + m * 16 + l15) * 32 + quad * 8];
#pragma unroll
        for (int n = 0; n < 4; ++n)
            bg[n] = *(const bf16x8*)&Bl[(wj * 64 + n * 16 + l15) * 32 + quad * 8];
#pragma unroll
        for (int m = 0; m < 4; ++m)
#pragma unroll
            for (int n = 0; n < 4; ++n)
                acc[m][n] = __builtin_amdgcn_mfma_f32_16x16x32_bf16(
                    af[m], bg[n], acc[m][n], 0, 0, 0);
        __syncthreads();   // compute done before next overwrite
    }

    // epilogue: per (i) argmax over this block's 64 j columns (per wave)
    // D frag: lane holds D[m=quad*4+r][n=l15] for each (mi,nj)
#pragma unroll
    for (int m = 0; m < 4; ++m) {
#pragma unroll
        for (int r = 0; r < 4; ++r) {
            float v = acc[m][0][r];
            int j = j0 + wj * 64 + l15;
#pragma unroll
            for (int n = 1; n < 4; ++n) {
                float vn = acc[m][n][r];
                int jn = j0 + wj * 64 + n * 16 + l15;
                if (vn > v) { v = vn; j = jn; }   // strict >: keeps smallest j
            }
            // reduce across the quad's 16 lanes (distinct j, same i)
#pragma unroll
            for (int msk = 1; msk < 16; msk <<= 1) {
                float ov = __shfl_xor(v, msk, 64);
                int   oj = __shfl_xor(j, msk, 64);
                if (ov > v || (ov == v && oj < j)) { v = ov; j = oj; }
            }
            if (l15 == 0) {
                int gi = i0 + wi * 64 + m * 16 + quad * 4 + r;
                uint32_t u = __float_as_uint(v);
                u = (u & 0x80000000u) ? ~u : (u | 0x80000000u);  // orderable f32
                unsigned long long packed =
                    ((unsigned long long)u << 32) | (uint32_t)(~(uint32_t)j);
                atomicMax(&best[gi], packed);  // ties -> larger ~j -> smaller j
            }
        }
    }
}

// ---- Kernel 4: gather + cos_loss (fp32 accumulate) ----
// block = 4 waves, each wave handles 16 i sequentially; grid 256 blocks
__global__ void loss_kernel(const bf16* __restrict__ at, const bf16* __restrict__ bnt,
                            const unsigned long long* __restrict__ best,
                            const float* __restrict__ denom_b,
                            const float* __restrict__ nb_raw,
                            float* __restrict__ out) {
    int w = threadIdx.x >> 6, lane = threadIdx.x & 63;
    float wsum = 0.f;
    for (int t = 0; t < 16; ++t) {
        int i = blockIdx.x * 64 + w * 16 + t;
        int j = (int)(~(uint32_t)best[i]);   // low 32 bits hold ~j
        float dp = 0.f, na2 = 0.f;
        for (int c = lane; c < CDIM; c += 64) {
            float av = (float)at[(size_t)i * CDIM + c];
            float bv = (float)bnt[(size_t)j * CDIM + c];
            dp = fmaf(av, bv, dp);
            na2 = fmaf(av, av, na2);
        }
#pragma unroll
        for (int m = 32; m; m >>= 1) {
            dp += __shfl_down(dp, m, 64);
            na2 += __shfl_down(na2, m, 64);
        }
        if (lane == 0) {
            float na = sqrtf(na2);
            float dot_raw = dp * denom_b[j];          // undo b_n scaling
            float cs = dot_raw / ((na + EPSF) * (nb_raw[j] + EPSF));
            wsum += (1.f - cs);
        }
    }
    __shared__ float red[4];
    if (lane == 0) red[w] = wsum;
    __syncthreads();
    if (threadIdx.x == 0) {
        float s = (red[0] + red[1] + red[2] + red[3]) * (1.0f / HW);
        atomicAdd(out, s);
    }
}

extern "C" void kernel_launch(void* const* d_in, const int* in_sizes, int n_in,
                              void* d_out, int out_size, void* d_ws, size_t ws_size,
                              hipStream_t stream) {
    const float* a = (const float*)d_in[0];
    const float* b = (const float*)d_in[1];
    char* ws = (char*)d_ws;

    const size_t AT_BYTES = (size_t)HW * CDIM * sizeof(bf16);   // 25165824
    bf16* at  = (bf16*)ws;
    bf16* bnt = (bf16*)(ws + AT_BYTES);
    float* denom_b = (float*)(ws + 2 * AT_BYTES);
    float* nb_raw  = (float*)(ws + 2 * AT_BYTES + HW * sizeof(float));
    unsigned long long* best =
        (unsigned long long*)(ws + 2 * AT_BYTES + 2 * HW * sizeof(float));

    hipMemsetAsync(best, 0, HW * sizeof(unsigned long long), stream);
    hipMemsetAsync(d_out, 0, out_size * sizeof(float), stream);

    colnorm_b<<<HW / 64, 256, 0, stream>>>(b, denom_b, nb_raw);
    dim3 tg(HW / 64, CDIM / 64);
    transpose_scale<<<tg, 256, 0, stream>>>(a, at, nullptr);
    transpose_scale<<<tg, 256, 0, stream>>>(b, bnt, denom_b);
    gemm_argmax<<<(HW / 128) * (HW / 128), 256, 0, stream>>>(at, bnt, best);
    loss_kernel<<<HW / 64, 256, 0, stream>>>(at, bnt, best, denom_b, nb_raw, (float*)d_out);
}

// Round 2
// 909.685 us; speedup vs baseline: 1.0774x; 1.0774x over previous
//
#include <hip/hip_runtime.h>
#include <stdint.h>

#define HW 16384
#define CDIM 768
#define EPSF 1e-8f

typedef __bf16 bf16;
typedef __bf16 bf16x8 __attribute__((ext_vector_type(8)));
typedef float f32x4 __attribute__((ext_vector_type(4)));

__device__ inline void async16(const bf16* g, bf16* l) {
    __builtin_amdgcn_global_load_lds(
        (const __attribute__((address_space(1))) uint32_t*)g,
        (__attribute__((address_space(3))) uint32_t*)l, 16, 0, 0);
}

// ---- Kernel 1: column norms of b (two-eps scheme) ----
__global__ void colnorm_b(const float* __restrict__ b,
                          float* __restrict__ denom_b,
                          float* __restrict__ nb_raw) {
    __shared__ float red[4][64];
    int tx = threadIdx.x & 63, ty = threadIdx.x >> 6;
    int j = blockIdx.x * 64 + tx;
    float s = 0.f;
    for (int c = ty; c < CDIM; c += 4) {
        float v = b[(size_t)c * HW + j];
        s = fmaf(v, v, s);
    }
    red[ty][tx] = s;
    __syncthreads();
    if (ty == 0) {
        s = red[0][tx] + red[1][tx] + red[2][tx] + red[3][tx];
        denom_b[j] = sqrtf(s + EPSF) + EPSF;   // matches reference b_n denominator
        nb_raw[j]  = sqrtf(s);                  // cos_loss's norm (eps outside)
    }
}

// ---- Kernel 2: transpose [C][HW] fp32 -> [HW][C] bf16, optional per-column scale ----
__global__ void transpose_scale(const float* __restrict__ src,
                                bf16* __restrict__ dst,
                                const float* __restrict__ denom) {
    __shared__ float tile[64][65];   // +1 pad: conflict-free
    int s0 = blockIdx.x * 64, c0 = blockIdx.y * 64;
    int tx = threadIdx.x & 63, ty = threadIdx.x >> 6;
#pragma unroll
    for (int p = 0; p < 16; ++p) {
        int cl = p * 4 + ty;
        tile[cl][tx] = src[(size_t)(c0 + cl) * HW + s0 + tx];
    }
    __syncthreads();
#pragma unroll
    for (int p = 0; p < 16; ++p) {
        int sl = p * 4 + ty;
        float sc = denom ? (1.0f / denom[s0 + sl]) : 1.0f;
        float v = tile[tx][sl] * sc;
        dst[(size_t)(s0 + sl) * CDIM + c0 + tx] = (bf16)v;
    }
}

// ---- Kernel 3: GEMM (a_t[i][c] . bn_t[j][c]) with argmax-over-j epilogue ----
// 128x128 tile, BK=32, 4 waves (2x2), 4x4 frags of mfma_f32_16x16x32_bf16.
// Block->tile mapping is XCD-aware: blockIdx%8 = XCD (round-robin dispatch
// heuristic); each XCD owns a 16-i-tile strip and rasters it in 4x8
// supertiles (12 tiles = 2.35 MB working set < 4 MB per-XCD L2) so staging
// traffic is served by L2 instead of Infinity Cache.
__global__ void __launch_bounds__(256)
gemm_argmax(const bf16* __restrict__ at, const bf16* __restrict__ bnt,
            unsigned long long* __restrict__ best) {
    __shared__ bf16 Al[128 * 32];
    __shared__ bf16 Bl[128 * 32];

    const int g = blockIdx.x;          // 0..16383
    const int xcd    = g & 7;
    const int s      = g >> 3;         // 0..2047 sequence within XCD
    const int super  = s >> 5;         // 0..63   (32 blocks / supertile)
    const int within = s & 31;
    const int si = super >> 4;         // 0..3    supertile row (4 i-tiles each)
    const int sj = super & 15;         // 0..15   supertile col (8 j-tiles each)
    const int it = xcd * 16 + si * 4 + (within & 3);
    const int jt = sj * 8 + (within >> 2);

    const int i0 = it * 128, j0 = jt * 128;
    const int tid = threadIdx.x;
    const int lane = tid & 63, w = tid >> 6;
    const int wi = w & 1, wj = w >> 1;
    const int quad = lane >> 4, l15 = lane & 15;

    f32x4 acc[4][4] = {};

    const int srow = (lane >> 2);
    const int scol = (lane & 3) * 8;
    const bf16* gA = at + (size_t)(i0 + w * 32 + srow) * CDIM + scol;
    const bf16* gB = bnt + (size_t)(j0 + w * 32 + srow) * CDIM + scol;
    bf16* lA = &Al[(w * 32) * 32];
    bf16* lB = &Bl[(w * 32) * 32];

    for (int kk = 0; kk < CDIM; kk += 32) {
        async16(gA + kk,             lA);
        async16(gA + 16 * CDIM + kk, lA + 16 * 32);
        async16(gB + kk,             lB);
        async16(gB + 16 * CDIM + kk, lB + 16 * 32);
        __syncthreads();   // drains vmcnt (global_load_lds) + barrier

        bf16x8 af[4], bg[4];
#pragma unroll
        for (int m = 0; m < 4; ++m)
            af[m] = *(const bf16x8*)&Al[(wi * 64 + m * 16 + l15) * 32 + quad * 8];
#pragma unroll
        for (int n = 0; n < 4; ++n)
            bg[n] = *(const bf16x8*)&Bl[(wj * 64 + n * 16 + l15) * 32 + quad * 8];
#pragma unroll
        for (int m = 0; m < 4; ++m)
#pragma unroll
            for (int n = 0; n < 4; ++n)
                acc[m][n] = __builtin_amdgcn_mfma_f32_16x16x32_bf16(
                    af[m], bg[n], acc[m][n], 0, 0, 0);
        __syncthreads();   // compute done before next overwrite
    }

    // epilogue: per-i argmax over this block's j columns
#pragma unroll
    for (int m = 0; m < 4; ++m) {
#pragma unroll
        for (int r = 0; r < 4; ++r) {
            float v = acc[m][0][r];
            int j = j0 + wj * 64 + l15;
#pragma unroll
            for (int n = 1; n < 4; ++n) {
                float vn = acc[m][n][r];
                int jn = j0 + wj * 64 + n * 16 + l15;
                if (vn > v) { v = vn; j = jn; }   // strict >: keeps smallest j
            }
#pragma unroll
            for (int msk = 1; msk < 16; msk <<= 1) {
                float ov = __shfl_xor(v, msk, 64);
                int   oj = __shfl_xor(j, msk, 64);
                if (ov > v || (ov == v && oj < j)) { v = ov; j = oj; }
            }
            if (l15 == 0) {
                int gi = i0 + wi * 64 + m * 16 + quad * 4 + r;
                uint32_t u = __float_as_uint(v);
                u = (u & 0x80000000u) ? ~u : (u | 0x80000000u);  // orderable f32
                unsigned long long packed =
                    ((unsigned long long)u << 32) | (uint32_t)(~(uint32_t)j);
                atomicMax(&best[gi], packed);  // ties -> larger ~j -> smaller j
            }
        }
    }
}

// ---- Kernel 4: gather + cos_loss (fp32 accumulate) ----
__global__ void loss_kernel(const bf16* __restrict__ at, const bf16* __restrict__ bnt,
                            const unsigned long long* __restrict__ best,
                            const float* __restrict__ denom_b,
                            const float* __restrict__ nb_raw,
                            float* __restrict__ out) {
    int w = threadIdx.x >> 6, lane = threadIdx.x & 63;
    float wsum = 0.f;
    for (int t = 0; t < 16; ++t) {
        int i = blockIdx.x * 64 + w * 16 + t;
        int j = (int)(~(uint32_t)best[i]);   // low 32 bits hold ~j
        float dp = 0.f, na2 = 0.f;
        for (int c = lane; c < CDIM; c += 64) {
            float av = (float)at[(size_t)i * CDIM + c];
            float bv = (float)bnt[(size_t)j * CDIM + c];
            dp = fmaf(av, bv, dp);
            na2 = fmaf(av, av, na2);
        }
#pragma unroll
        for (int m = 32; m; m >>= 1) {
            dp += __shfl_down(dp, m, 64);
            na2 += __shfl_down(na2, m, 64);
        }
        if (lane == 0) {
            float na = sqrtf(na2);
            float dot_raw = dp * denom_b[j];          // undo b_n scaling
            float cs = dot_raw / ((na + EPSF) * (nb_raw[j] + EPSF));
            wsum += (1.f - cs);
        }
    }
    __shared__ float red[4];
    if (lane == 0) red[w] = wsum;
    __syncthreads();
    if (threadIdx.x == 0) {
        float s = (red[0] + red[1] + red[2] + red[3]) * (1.0f / HW);
        atomicAdd(out, s);
    }
}

extern "C" void kernel_launch(void* const* d_in, const int* in_sizes, int n_in,
                              void* d_out, int out_size, void* d_ws, size_t ws_size,
                              hipStream_t stream) {
    const float* a = (const float*)d_in[0];
    const float* b = (const float*)d_in[1];
    char* ws = (char*)d_ws;

    const size_t AT_BYTES = (size_t)HW * CDIM * sizeof(bf16);   // 25165824
    bf16* at  = (bf16*)ws;
    bf16* bnt = (bf16*)(ws + AT_BYTES);
    float* denom_b = (float*)(ws + 2 * AT_BYTES);
    float* nb_raw  = (float*)(ws + 2 * AT_BYTES + HW * sizeof(float));
    unsigned long long* best =
        (unsigned long long*)(ws + 2 * AT_BYTES + 2 * HW * sizeof(float));

    hipMemsetAsync(best, 0, HW * sizeof(unsigned long long), stream);
    hipMemsetAsync(d_out, 0, out_size * sizeof(float), stream);

    colnorm_b<<<HW / 64, 256, 0, stream>>>(b, denom_b, nb_raw);
    dim3 tg(HW / 64, CDIM / 64);
    transpose_scale<<<tg, 256, 0, stream>>>(a, at, nullptr);
    transpose_scale<<<tg, 256, 0, stream>>>(b, bnt, denom_b);
    gemm_argmax<<<(HW / 128) * (HW / 128), 256, 0, stream>>>(at, bnt, best);
    loss_kernel<<<HW / 64, 256, 0, stream>>>(at, bnt, best, denom_b, nb_raw, (float*)d_out);
}

// Round 3
// 892.160 us; speedup vs baseline: 1.0986x; 1.0196x over previous
//
#include <hip/hip_runtime.h>
#include <stdint.h>

#define HW 16384
#define CDIM 768
#define EPSF 1e-8f

typedef __bf16 bf16;
typedef __bf16 bf16x8 __attribute__((ext_vector_type(8)));
typedef float f32x4 __attribute__((ext_vector_type(4)));

__device__ inline void async16(const bf16* g, bf16* l) {
    __builtin_amdgcn_global_load_lds(
        (const __attribute__((address_space(1))) uint32_t*)g,
        (__attribute__((address_space(3))) uint32_t*)l, 16, 0, 0);
}

// ---- Kernel 1: column norms of b (two-eps scheme) ----
__global__ void colnorm_b(const float* __restrict__ b,
                          float* __restrict__ denom_b,
                          float* __restrict__ nb_raw) {
    __shared__ float red[4][64];
    int tx = threadIdx.x & 63, ty = threadIdx.x >> 6;
    int j = blockIdx.x * 64 + tx;
    float s = 0.f;
    for (int c = ty; c < CDIM; c += 4) {
        float v = b[(size_t)c * HW + j];
        s = fmaf(v, v, s);
    }
    red[ty][tx] = s;
    __syncthreads();
    if (ty == 0) {
        s = red[0][tx] + red[1][tx] + red[2][tx] + red[3][tx];
        denom_b[j] = sqrtf(s + EPSF) + EPSF;   // matches reference b_n denominator
        nb_raw[j]  = sqrtf(s);                  // cos_loss's norm (eps outside)
    }
}

// ---- Kernel 2: transpose [C][HW] fp32 -> [HW][C] bf16, optional per-column scale ----
__global__ void transpose_scale(const float* __restrict__ src,
                                bf16* __restrict__ dst,
                                const float* __restrict__ denom) {
    __shared__ float tile[64][65];   // +1 pad: conflict-free
    int s0 = blockIdx.x * 64, c0 = blockIdx.y * 64;
    int tx = threadIdx.x & 63, ty = threadIdx.x >> 6;
#pragma unroll
    for (int p = 0; p < 16; ++p) {
        int cl = p * 4 + ty;
        tile[cl][tx] = src[(size_t)(c0 + cl) * HW + s0 + tx];
    }
    __syncthreads();
#pragma unroll
    for (int p = 0; p < 16; ++p) {
        int sl = p * 4 + ty;
        float sc = denom ? (1.0f / denom[s0 + sl]) : 1.0f;
        float v = tile[tx][sl] * sc;
        dst[(size_t)(s0 + sl) * CDIM + c0 + tx] = (bf16)v;
    }
}

// ---- Kernel 3: GEMM (a_t[i][c] . bn_t[j][c]) with argmax-over-j epilogue ----
// 128x128 tile, BK=64 as TWO 32-wide LDS panels (keeps 64 B row stride for
// conflict-unchanged ds_read_b128), 4 waves (2x2), 4x4 frags of
// mfma_f32_16x16x32_bf16. 12 barrier-drains instead of 24: each vmcnt(0)
// drain now amortizes 2x the MFMA work (latency-serialization was the
// limiter at BK=32: ~900 cyc exposed wait vs ~250 cyc compute per iter).
// XCD-aware swizzle: blockIdx%8 = XCD; 4x8-tile supertiles (<4 MB L2).
__global__ void __launch_bounds__(256)
gemm_argmax(const bf16* __restrict__ at, const bf16* __restrict__ bnt,
            unsigned long long* __restrict__ best) {
    __shared__ bf16 Al[2][128 * 32];
    __shared__ bf16 Bl[2][128 * 32];

    const int g = blockIdx.x;          // 0..16383
    const int xcd    = g & 7;
    const int s      = g >> 3;         // 0..2047 sequence within XCD
    const int super  = s >> 5;         // 0..63   (32 blocks / supertile)
    const int within = s & 31;
    const int si = super >> 4;         // 0..3    supertile row (4 i-tiles each)
    const int sj = super & 15;         // 0..15   supertile col (8 j-tiles each)
    const int it = xcd * 16 + si * 4 + (within & 3);
    const int jt = sj * 8 + (within >> 2);

    const int i0 = it * 128, j0 = jt * 128;
    const int tid = threadIdx.x;
    const int lane = tid & 63, w = tid >> 6;
    const int wi = w & 1, wj = w >> 1;
    const int quad = lane >> 4, l15 = lane & 15;

    f32x4 acc[4][4] = {};

    const int srow = (lane >> 2);
    const int scol = (lane & 3) * 8;
    const bf16* gA = at + (size_t)(i0 + w * 32 + srow) * CDIM + scol;
    const bf16* gB = bnt + (size_t)(j0 + w * 32 + srow) * CDIM + scol;
    const int lbase = (w * 32) * 32;   // wave's 32-row slice within a panel

    for (int kk = 0; kk < CDIM; kk += 64) {
#pragma unroll
        for (int p = 0; p < 2; ++p) {
            const int kb = kk + p * 32;
            async16(gA + kb,             &Al[p][lbase]);
            async16(gA + 16 * CDIM + kb, &Al[p][lbase + 16 * 32]);
            async16(gB + kb,             &Bl[p][lbase]);
            async16(gB + 16 * CDIM + kb, &Bl[p][lbase + 16 * 32]);
        }
        __syncthreads();   // single drain for all 32 KB of this K-iter

#pragma unroll
        for (int p = 0; p < 2; ++p) {
            bf16x8 af[4], bg[4];
#pragma unroll
            for (int m = 0; m < 4; ++m)
                af[m] = *(const bf16x8*)&Al[p][(wi * 64 + m * 16 + l15) * 32 + quad * 8];
#pragma unroll
            for (int n = 0; n < 4; ++n)
                bg[n] = *(const bf16x8*)&Bl[p][(wj * 64 + n * 16 + l15) * 32 + quad * 8];
#pragma unroll
            for (int m = 0; m < 4; ++m)
#pragma unroll
                for (int n = 0; n < 4; ++n)
                    acc[m][n] = __builtin_amdgcn_mfma_f32_16x16x32_bf16(
                        af[m], bg[n], acc[m][n], 0, 0, 0);
        }
        __syncthreads();   // compute done before next overwrite
    }

    // epilogue: per-i argmax over this block's j columns
#pragma unroll
    for (int m = 0; m < 4; ++m) {
#pragma unroll
        for (int r = 0; r < 4; ++r) {
            float v = acc[m][0][r];
            int j = j0 + wj * 64 + l15;
#pragma unroll
            for (int n = 1; n < 4; ++n) {
                float vn = acc[m][n][r];
                int jn = j0 + wj * 64 + n * 16 + l15;
                if (vn > v) { v = vn; j = jn; }   // strict >: keeps smallest j
            }
#pragma unroll
            for (int msk = 1; msk < 16; msk <<= 1) {
                float ov = __shfl_xor(v, msk, 64);
                int   oj = __shfl_xor(j, msk, 64);
                if (ov > v || (ov == v && oj < j)) { v = ov; j = oj; }
            }
            if (l15 == 0) {
                int gi = i0 + wi * 64 + m * 16 + quad * 4 + r;
                uint32_t u = __float_as_uint(v);
                u = (u & 0x80000000u) ? ~u : (u | 0x80000000u);  // orderable f32
                unsigned long long packed =
                    ((unsigned long long)u << 32) | (uint32_t)(~(uint32_t)j);
                atomicMax(&best[gi], packed);  // ties -> larger ~j -> smaller j
            }
        }
    }
}

// ---- Kernel 4: gather + cos_loss (fp32 accumulate) ----
__global__ void loss_kernel(const bf16* __restrict__ at, const bf16* __restrict__ bnt,
                            const unsigned long long* __restrict__ best,
                            const float* __restrict__ denom_b,
                            const float* __restrict__ nb_raw,
                            float* __restrict__ out) {
    int w = threadIdx.x >> 6, lane = threadIdx.x & 63;
    float wsum = 0.f;
    for (int t = 0; t < 16; ++t) {
        int i = blockIdx.x * 64 + w * 16 + t;
        int j = (int)(~(uint32_t)best[i]);   // low 32 bits hold ~j
        float dp = 0.f, na2 = 0.f;
        for (int c = lane; c < CDIM; c += 64) {
            float av = (float)at[(size_t)i * CDIM + c];
            float bv = (float)bnt[(size_t)j * CDIM + c];
            dp = fmaf(av, bv, dp);
            na2 = fmaf(av, av, na2);
        }
#pragma unroll
        for (int m = 32; m; m >>= 1) {
            dp += __shfl_down(dp, m, 64);
            na2 += __shfl_down(na2, m, 64);
        }
        if (lane == 0) {
            float na = sqrtf(na2);
            float dot_raw = dp * denom_b[j];          // undo b_n scaling
            float cs = dot_raw / ((na + EPSF) * (nb_raw[j] + EPSF));
            wsum += (1.f - cs);
        }
    }
    __shared__ float red[4];
    if (lane == 0) red[w] = wsum;
    __syncthreads();
    if (threadIdx.x == 0) {
        float s = (red[0] + red[1] + red[2] + red[3]) * (1.0f / HW);
        atomicAdd(out, s);
    }
}

extern "C" void kernel_launch(void* const* d_in, const int* in_sizes, int n_in,
                              void* d_out, int out_size, void* d_ws, size_t ws_size,
                              hipStream_t stream) {
    const float* a = (const float*)d_in[0];
    const float* b = (const float*)d_in[1];
    char* ws = (char*)d_ws;

    const size_t AT_BYTES = (size_t)HW * CDIM * sizeof(bf16);   // 25165824
    bf16* at  = (bf16*)ws;
    bf16* bnt = (bf16*)(ws + AT_BYTES);
    float* denom_b = (float*)(ws + 2 * AT_BYTES);
    float* nb_raw  = (float*)(ws + 2 * AT_BYTES + HW * sizeof(float));
    unsigned long long* best =
        (unsigned long long*)(ws + 2 * AT_BYTES + 2 * HW * sizeof(float));

    hipMemsetAsync(best, 0, HW * sizeof(unsigned long long), stream);
    hipMemsetAsync(d_out, 0, out_size * sizeof(float), stream);

    colnorm_b<<<HW / 64, 256, 0, stream>>>(b, denom_b, nb_raw);
    dim3 tg(HW / 64, CDIM / 64);
    transpose_scale<<<tg, 256, 0, stream>>>(a, at, nullptr);
    transpose_scale<<<tg, 256, 0, stream>>>(b, bnt, denom_b);
    gemm_argmax<<<(HW / 128) * (HW / 128), 256, 0, stream>>>(at, bnt, best);
    loss_kernel<<<HW / 64, 256, 0, stream>>>(at, bnt, best, denom_b, nb_raw, (float*)d_out);
}

// Round 4
// 755.812 us; speedup vs baseline: 1.2968x; 1.1804x over previous
//
#include <hip/hip_runtime.h>
#include <stdint.h>

#define HW 16384
#define CDIM 768
#define EPSF 1e-8f

typedef float f32x4 __attribute__((ext_vector_type(4)));

__device__ inline void async16(const void* g, void* l) {
    __builtin_amdgcn_global_load_lds(
        (const __attribute__((address_space(1))) uint32_t*)g,
        (__attribute__((address_space(3))) uint32_t*)l, 16, 0, 0);
}

__device__ inline uint8_t to_fp8(float v) {
    // OCP e4m3fn via HW pack (RNE); take low byte
    return (uint8_t)(__builtin_amdgcn_cvt_pk_fp8_f32(v, v, 0, false) & 0xff);
}

// ---- Kernel 1: column norms over channel dim; denom (two-eps) optional ----
__global__ void colnorm(const float* __restrict__ src,
                        float* __restrict__ denom_out,
                        float* __restrict__ raw_out) {
    __shared__ float red[4][64];
    int tx = threadIdx.x & 63, ty = threadIdx.x >> 6;
    int j = blockIdx.x * 64 + tx;
    float s = 0.f;
    for (int c = ty; c < CDIM; c += 4) {
        float v = src[(size_t)c * HW + j];
        s = fmaf(v, v, s);
    }
    red[ty][tx] = s;
    __syncthreads();
    if (ty == 0) {
        s = red[0][tx] + red[1][tx] + red[2][tx] + red[3][tx];
        if (denom_out) denom_out[j] = sqrtf(s + EPSF) + EPSF; // b_n denominator
        raw_out[j] = sqrtf(s);                                // cos_loss norm
    }
}

// ---- Kernel 2: transpose [C][HW] fp32 -> [HW][C] fp8 e4m3, scaled ----
// scale = mult / denom[col] (denom nullable). a: mult=16; b: mult=8/denom_b.
// Scaling centers values in e4m3's normal range (fewer subnormals).
__global__ void transpose_fp8(const float* __restrict__ src,
                              uint8_t* __restrict__ dst,
                              const float* __restrict__ denom,
                              float mult) {
    __shared__ float tile[64][65];   // +1 pad: conflict-free
    int s0 = blockIdx.x * 64, c0 = blockIdx.y * 64;
    int tx = threadIdx.x & 63, ty = threadIdx.x >> 6;
#pragma unroll
    for (int p = 0; p < 16; ++p) {
        int cl = p * 4 + ty;
        tile[cl][tx] = src[(size_t)(c0 + cl) * HW + s0 + tx];
    }
    __syncthreads();
#pragma unroll
    for (int p = 0; p < 16; ++p) {
        int sl = p * 4 + ty;
        float sc = denom ? (mult / denom[s0 + sl]) : mult;
        dst[(size_t)(s0 + sl) * CDIM + c0 + tx] = to_fp8(tile[tx][sl] * sc);
    }
}

// ---- Kernel 3: fp8 GEMM (at8[i][c] . bn8[j][c]) + argmax-over-j epilogue ----
// 128x128 tile, BK=64 (two 32-byte panels), 4 waves (2x2), 4x4 frags of
// mfma_f32_16x16x32_fp8_fp8. fp8 halves staged bytes per vmcnt(0) drain
// (4 async16/wave/iter) and halves frag VGPRs -> ~128 regs incl 64 AGPR
// -> 4 waves/SIMD (launch_bounds(256,4)): more latency overlap than the
// bf16 version's 3. XCD swizzle: blockIdx%8 = XCD; 4x8-tile supertiles.
__global__ void __launch_bounds__(256, 4)
gemm_argmax(const uint8_t* __restrict__ at8, const uint8_t* __restrict__ bn8,
            unsigned long long* __restrict__ best) {
    __shared__ uint8_t Al[2][128 * 32];
    __shared__ uint8_t Bl[2][128 * 32];

    const int g = blockIdx.x;          // 0..16383
    const int xcd    = g & 7;
    const int s      = g >> 3;
    const int super  = s >> 5;         // 32 blocks / supertile
    const int within = s & 31;
    const int si = super >> 4;         // 4 i-tiles per supertile row
    const int sj = super & 15;         // 8 j-tiles per supertile col
    const int it = xcd * 16 + si * 4 + (within & 3);
    const int jt = sj * 8 + (within >> 2);

    const int i0 = it * 128, j0 = jt * 128;
    const int tid = threadIdx.x;
    const int lane = tid & 63, w = tid >> 6;
    const int wi = w & 1, wj = w >> 1;
    const int quad = lane >> 4, l15 = lane & 15;

    f32x4 acc[4][4] = {};

    // staging: lane l -> row l>>1, 16B half (l&1) of a 32B fp8 row
    const int srow = lane >> 1;
    const int scol = (lane & 1) * 16;
    const uint8_t* gA = at8 + (size_t)(i0 + w * 32 + srow) * CDIM + scol;
    const uint8_t* gB = bn8 + (size_t)(j0 + w * 32 + srow) * CDIM + scol;
    const int lbase = w * 32 * 32;     // wave's 32-row slice (1 KB) in a panel

    for (int kk = 0; kk < CDIM; kk += 64) {
#pragma unroll
        for (int p = 0; p < 2; ++p) {
            const int kb = kk + p * 32;
            async16(gA + kb, &Al[p][lbase]);
            async16(gB + kb, &Bl[p][lbase]);
        }
        __syncthreads();

#pragma unroll
        for (int p = 0; p < 2; ++p) {
            long af[4], bg[4];
#pragma unroll
            for (int m = 0; m < 4; ++m)
                af[m] = *(const long*)&Al[p][(wi * 64 + m * 16 + l15) * 32 + quad * 8];
#pragma unroll
            for (int n = 0; n < 4; ++n)
                bg[n] = *(const long*)&Bl[p][(wj * 64 + n * 16 + l15) * 32 + quad * 8];
#pragma unroll
            for (int m = 0; m < 4; ++m)
#pragma unroll
                for (int n = 0; n < 4; ++n)
                    acc[m][n] = __builtin_amdgcn_mfma_f32_16x16x32_fp8_fp8(
                        af[m], bg[n], acc[m][n], 0, 0, 0);
        }
        __syncthreads();
    }

    // epilogue: per-i argmax over this block's j columns
#pragma unroll
    for (int m = 0; m < 4; ++m) {
#pragma unroll
        for (int r = 0; r < 4; ++r) {
            float v = acc[m][0][r];
            int j = j0 + wj * 64 + l15;
#pragma unroll
            for (int n = 1; n < 4; ++n) {
                float vn = acc[m][n][r];
                int jn = j0 + wj * 64 + n * 16 + l15;
                if (vn > v) { v = vn; j = jn; }   // strict >: keeps smallest j
            }
#pragma unroll
            for (int msk = 1; msk < 16; msk <<= 1) {
                float ov = __shfl_xor(v, msk, 64);
                int   oj = __shfl_xor(j, msk, 64);
                if (ov > v || (ov == v && oj < j)) { v = ov; j = oj; }
            }
            if (l15 == 0) {
                int gi = i0 + wi * 64 + m * 16 + quad * 4 + r;
                uint32_t u = __float_as_uint(v);
                u = (u & 0x80000000u) ? ~u : (u | 0x80000000u);  // orderable f32
                unsigned long long packed =
                    ((unsigned long long)u << 32) | (uint32_t)(~(uint32_t)j);
                atomicMax(&best[gi], packed);  // ties -> larger ~j -> smaller j
            }
        }
    }
}

// ---- Kernel 4: final loss directly from stored argmax dot (no gather) ----
// v = 128 * dot(a_i, b_j/denom_b[j]) in fp8 precision (fp32-accumulated);
// cossim = v*denom_b[j]/128 / ((||a_i||+eps)(||b_j||+eps)) with exact norms.
__global__ void loss_reduce(const unsigned long long* __restrict__ best,
                            const float* __restrict__ denom_b,
                            const float* __restrict__ nb_raw,
                            const float* __restrict__ na_raw,
                            float* __restrict__ out) {
    int i = blockIdx.x * 256 + threadIdx.x;
    unsigned long long pk = best[i];
    uint32_t x = (uint32_t)(pk >> 32);
    float v = (x & 0x80000000u) ? __uint_as_float(x & 0x7fffffffu)
                                : __uint_as_float(~x);
    int j = (int)(~(uint32_t)pk);
    float dot = v * denom_b[j] * (1.0f / 128.0f);
    float cs = dot / ((na_raw[i] + EPSF) * (nb_raw[j] + EPSF));
    float term = 1.0f - cs;
#pragma unroll
    for (int m = 32; m; m >>= 1) term += __shfl_down(term, m, 64);
    __shared__ float red[4];
    int wv = threadIdx.x >> 6, lane = threadIdx.x & 63;
    if (lane == 0) red[wv] = term;
    __syncthreads();
    if (threadIdx.x == 0) {
        float ssum = (red[0] + red[1] + red[2] + red[3]) * (1.0f / HW);
        atomicAdd(out, ssum);
    }
}

extern "C" void kernel_launch(void* const* d_in, const int* in_sizes, int n_in,
                              void* d_out, int out_size, void* d_ws, size_t ws_size,
                              hipStream_t stream) {
    const float* a = (const float*)d_in[0];
    const float* b = (const float*)d_in[1];
    char* ws = (char*)d_ws;

    const size_t T_BYTES = (size_t)HW * CDIM;   // 12.58 MB per fp8 matrix
    uint8_t* at8 = (uint8_t*)ws;
    uint8_t* bn8 = (uint8_t*)(ws + T_BYTES);
    float* denom_b = (float*)(ws + 2 * T_BYTES);
    float* nb_raw  = (float*)(ws + 2 * T_BYTES + HW * sizeof(float));
    float* na_raw  = (float*)(ws + 2 * T_BYTES + 2 * HW * sizeof(float));
    unsigned long long* best =
        (unsigned long long*)(ws + 2 * T_BYTES + 3 * HW * sizeof(float));

    hipMemsetAsync(best, 0, HW * sizeof(unsigned long long), stream);
    hipMemsetAsync(d_out, 0, out_size * sizeof(float), stream);

    colnorm<<<HW / 64, 256, 0, stream>>>(b, denom_b, nb_raw);
    colnorm<<<HW / 64, 256, 0, stream>>>(a, nullptr, na_raw);
    dim3 tg(HW / 64, CDIM / 64);
    transpose_fp8<<<tg, 256, 0, stream>>>(a, at8, nullptr, 16.0f);
    transpose_fp8<<<tg, 256, 0, stream>>>(b, bn8, denom_b, 8.0f);
    gemm_argmax<<<(HW / 128) * (HW / 128), 256, 0, stream>>>(at8, bn8, best);
    loss_reduce<<<HW / 256, 256, 0, stream>>>(best, denom_b, nb_raw, na_raw,
                                              (float*)d_out);
}

// Round 5
// 570.496 us; speedup vs baseline: 1.7180x; 1.3248x over previous
//
#include <hip/hip_runtime.h>
#include <stdint.h>

#define HW 16384
#define CDIM 768
#define EPSF 1e-8f

typedef float f32x4 __attribute__((ext_vector_type(4)));

__device__ inline void async16(const void* g, void* l) {
    __builtin_amdgcn_global_load_lds(
        (const __attribute__((address_space(1))) uint32_t*)g,
        (__attribute__((address_space(3))) uint32_t*)l, 16, 0, 0);
}

__device__ inline uint32_t pk4_fp8(float v0, float v1, float v2, float v3) {
    uint32_t r = __builtin_amdgcn_cvt_pk_fp8_f32(v0, v1, 0, false);
    r = __builtin_amdgcn_cvt_pk_fp8_f32(v2, v3, r, true);
    return r;   // bytes [v0,v1,v2,v3] little-endian
}

// ---- Kernel 1: fused transpose [C][HW] fp32 -> [HW][C] fp8 + column sum-sq ----
// z=0: a (scale x16), z=1: b (scale x8, RAW — normalization moved to GEMM
// epilogue so no denom dependency). Column sum of squares (raw values)
// accumulated via shuffle-reduce + one atomicAdd per (row, c-tile).
// u32 stores: 4 packed fp8 per thread (vs byte stores before).
__global__ void __launch_bounds__(256)
transpose_fp8_norm(const float* __restrict__ a, const float* __restrict__ b,
                   uint8_t* __restrict__ at8, uint8_t* __restrict__ bn8,
                   float* __restrict__ sumsq_a, float* __restrict__ sumsq_b) {
    const int z = blockIdx.z;
    const float* src = z ? b : a;
    uint8_t* dst = z ? bn8 : at8;
    float* sums = z ? sumsq_b : sumsq_a;
    const float mult = z ? 8.0f : 16.0f;

    __shared__ float tile[64][65];   // [channel][spatial], +1 pad
    const int s0 = blockIdx.x * 64, c0 = blockIdx.y * 64;
    const int tx = threadIdx.x & 63, ty = threadIdx.x >> 6;
#pragma unroll
    for (int p = 0; p < 16; ++p) {
        int cl = p * 4 + ty;
        tile[cl][tx] = src[(size_t)(c0 + cl) * HW + s0 + tx];
    }
    __syncthreads();

    const int chgrp = tx & 15, rowsub = tx >> 4;
    uint32_t* dst32 = (uint32_t*)dst;
#pragma unroll
    for (int p = 0; p < 4; ++p) {
        int sl = p * 16 + ty * 4 + rowsub;
        float v0 = tile[chgrp * 4 + 0][sl];
        float v1 = tile[chgrp * 4 + 1][sl];
        float v2 = tile[chgrp * 4 + 2][sl];
        float v3 = tile[chgrp * 4 + 3][sl];
        float part = v0 * v0 + v1 * v1 + v2 * v2 + v3 * v3;  // raw sum-sq
        dst32[(size_t)(s0 + sl) * (CDIM / 4) + (c0 >> 2) + chgrp] =
            pk4_fp8(v0 * mult, v1 * mult, v2 * mult, v3 * mult);
#pragma unroll
        for (int m = 1; m < 16; m <<= 1) part += __shfl_xor(part, m, 64);
        if (chgrp == 0) atomicAdd(&sums[s0 + sl], part);
    }
}

// ---- Kernel 2: fp8 GEMM (at8[i][c] . b8[j][c]) + normalize + argmax epilogue ----
// 128x128 tile, BK=64 (two 32B panels), 4 waves (2x2), 4x4 frags of
// mfma_f32_16x16x32_fp8_fp8, 4 blocks/CU. LDS XOR-swizzle: slot l stages
// global 16B chunk (l&1)^((l>>3)&1) of row l>>1, so b64 frag reads at
// R*32 + ((quad>>1)^((l15>>2)&1))*16 + (quad&1)*8 are 2-way max (= free)
// instead of 4-way (1.5e8 conflict cycles in the unswizzled version).
// Per-j normalization (1/(sqrt(ssq+eps)+eps)) applied in epilogue.
__global__ void __launch_bounds__(256, 4)
gemm_argmax(const uint8_t* __restrict__ at8, const uint8_t* __restrict__ bn8,
            const float* __restrict__ sumsq_b,
            unsigned long long* __restrict__ best) {
    __shared__ uint8_t Al[2][128 * 32];
    __shared__ uint8_t Bl[2][128 * 32];

    const int g = blockIdx.x;          // 0..16383
    const int xcd    = g & 7;
    const int s      = g >> 3;
    const int super  = s >> 5;         // 32 blocks / supertile
    const int within = s & 31;
    const int si = super >> 4;         // 4 i-tiles per supertile row
    const int sj = super & 15;         // 8 j-tiles per supertile col
    const int it = xcd * 16 + si * 4 + (within & 3);
    const int jt = sj * 8 + (within >> 2);

    const int i0 = it * 128, j0 = jt * 128;
    const int tid = threadIdx.x;
    const int lane = tid & 63, w = tid >> 6;
    const int wi = w & 1, wj = w >> 1;
    const int quad = lane >> 4, l15 = lane & 15;

    f32x4 acc[4][4] = {};

    // staging with XOR-swizzled source chunk (see header comment)
    const int srow = lane >> 1;
    const int scol = ((lane ^ (lane >> 3)) & 1) * 16;
    const uint8_t* gA = at8 + (size_t)(i0 + w * 32 + srow) * CDIM + scol;
    const uint8_t* gB = bn8 + (size_t)(j0 + w * 32 + srow) * CDIM + scol;
    const int lbase = w * 32 * 32;     // wave's 32-row slice (1 KB) in a panel

    // swizzled frag-read chunk select (row-dependent part folds to l15)
    const int swzA = ((quad >> 1) ^ ((l15 >> 2) & 1)) * 16 + (quad & 1) * 8;

    for (int kk = 0; kk < CDIM; kk += 64) {
#pragma unroll
        for (int p = 0; p < 2; ++p) {
            const int kb = kk + p * 32;
            async16(gA + kb, &Al[p][lbase]);
            async16(gB + kb, &Bl[p][lbase]);
        }
        __syncthreads();

#pragma unroll
        for (int p = 0; p < 2; ++p) {
            long af[4], bg[4];
#pragma unroll
            for (int m = 0; m < 4; ++m)
                af[m] = *(const long*)&Al[p][(wi * 64 + m * 16 + l15) * 32 + swzA];
#pragma unroll
            for (int n = 0; n < 4; ++n)
                bg[n] = *(const long*)&Bl[p][(wj * 64 + n * 16 + l15) * 32 + swzA];
#pragma unroll
            for (int m = 0; m < 4; ++m)
#pragma unroll
                for (int n = 0; n < 4; ++n)
                    acc[m][n] = __builtin_amdgcn_mfma_f32_16x16x32_fp8_fp8(
                        af[m], bg[n], acc[m][n], 0, 0, 0);
        }
        __syncthreads();
    }

    // epilogue: normalize by per-j denom, then argmax over this block's j's
    float invd[4];
#pragma unroll
    for (int n = 0; n < 4; ++n) {
        float sq = sumsq_b[j0 + wj * 64 + n * 16 + l15];
        invd[n] = 1.0f / (sqrtf(sq + EPSF) + EPSF);
    }
#pragma unroll
    for (int m = 0; m < 4; ++m) {
#pragma unroll
        for (int r = 0; r < 4; ++r) {
            float v = acc[m][0][r] * invd[0];
            int j = j0 + wj * 64 + l15;
#pragma unroll
            for (int n = 1; n < 4; ++n) {
                float vn = acc[m][n][r] * invd[n];
                int jn = j0 + wj * 64 + n * 16 + l15;
                if (vn > v) { v = vn; j = jn; }   // strict >: keeps smallest j
            }
#pragma unroll
            for (int msk = 1; msk < 16; msk <<= 1) {
                float ov = __shfl_xor(v, msk, 64);
                int   oj = __shfl_xor(j, msk, 64);
                if (ov > v || (ov == v && oj < j)) { v = ov; j = oj; }
            }
            if (l15 == 0) {
                int gi = i0 + wi * 64 + m * 16 + quad * 4 + r;
                uint32_t u = __float_as_uint(v);
                u = (u & 0x80000000u) ? ~u : (u | 0x80000000u);  // orderable f32
                unsigned long long packed =
                    ((unsigned long long)u << 32) | (uint32_t)(~(uint32_t)j);
                atomicMax(&best[gi], packed);  // ties -> larger ~j -> smaller j
            }
        }
    }
}

// ---- Kernel 3: final loss from stored argmax dot (no gather) ----
// stored v = 128 * dot(a_i, b_j) / denom_b[j]  (fp8 dot, fp32 denom)
__global__ void loss_reduce(const unsigned long long* __restrict__ best,
                            const float* __restrict__ sumsq_a,
                            const float* __restrict__ sumsq_b,
                            float* __restrict__ out) {
    int i = blockIdx.x * 256 + threadIdx.x;
    unsigned long long pk = best[i];
    uint32_t x = (uint32_t)(pk >> 32);
    float v = (x & 0x80000000u) ? __uint_as_float(x & 0x7fffffffu)
                                : __uint_as_float(~x);
    int j = (int)(~(uint32_t)pk);
    float sb = sumsq_b[j];
    float denb = sqrtf(sb + EPSF) + EPSF;
    float dot = v * denb * (1.0f / 128.0f);
    float cs = dot / ((sqrtf(sumsq_a[i]) + EPSF) * (sqrtf(sb) + EPSF));
    float term = 1.0f - cs;
#pragma unroll
    for (int m = 32; m; m >>= 1) term += __shfl_down(term, m, 64);
    __shared__ float red[4];
    int wv = threadIdx.x >> 6, lane = threadIdx.x & 63;
    if (lane == 0) red[wv] = term;
    __syncthreads();
    if (threadIdx.x == 0) {
        float ssum = (red[0] + red[1] + red[2] + red[3]) * (1.0f / HW);
        atomicAdd(out, ssum);
    }
}

extern "C" void kernel_launch(void* const* d_in, const int* in_sizes, int n_in,
                              void* d_out, int out_size, void* d_ws, size_t ws_size,
                              hipStream_t stream) {
    const float* a = (const float*)d_in[0];
    const float* b = (const float*)d_in[1];
    char* ws = (char*)d_ws;

    const size_t T_BYTES = (size_t)HW * CDIM;   // 12.58 MB per fp8 matrix
    uint8_t* at8 = (uint8_t*)ws;
    uint8_t* bn8 = (uint8_t*)(ws + T_BYTES);
    float* sumsq_a = (float*)(ws + 2 * T_BYTES);
    float* sumsq_b = (float*)(ws + 2 * T_BYTES + HW * sizeof(float));
    unsigned long long* best =
        (unsigned long long*)(ws + 2 * T_BYTES + 2 * HW * sizeof(float));

    // zero sumsq_a + sumsq_b + best in one contiguous memset
    hipMemsetAsync(sumsq_a, 0, 2 * HW * sizeof(float) + HW * sizeof(unsigned long long),
                   stream);
    hipMemsetAsync(d_out, 0, out_size * sizeof(float), stream);

    dim3 tg(HW / 64, CDIM / 64, 2);
    transpose_fp8_norm<<<tg, 256, 0, stream>>>(a, b, at8, bn8, sumsq_a, sumsq_b);
    gemm_argmax<<<(HW / 128) * (HW / 128), 256, 0, stream>>>(at8, bn8, sumsq_b, best);
    loss_reduce<<<HW / 256, 256, 0, stream>>>(best, sumsq_a, sumsq_b, (float*)d_out);
}